// Round 12
// baseline (8515.738 us; speedup 1.0000x reference)
//
#include <hip/hip_runtime.h>

// SNN-MNIST forward + STDP, MI355X persistent cooperative kernel.
// Round 16: MEASUREMENT ROUND (differential amplification). r15 source,
// byte-identical semantics, plus a duplicated phase-2 inner bb-loop into
// DEAD accumulators with asm-laundered base offsets (defeats ds_read CSE)
// and asm keep-alive (defeats DCE, rule #17). The dur delta vs r15 (6660)
// measures phase-2 inner's marginal cost directly:
//   +6-7 us/step -> LDS-throughput-bound -> retile next
//   +3-4 us/step -> issue-bound          -> retile + fold next
//   +<=1 us/step -> hidden; amplify gather next
// All state arithmetic identical to r15 (absmax must be 4.0).

#define T_STEPS 200
#define BATCH   256
#define INQ     784
#define NOUT    400
#define NP      512
#define GRID    256
#define NTHR    512

// ws layout (float offsets)
#define OFF_WT    0            // Wt [785][512] (row 784 = zero pad for gather)
#define OFF_SYN   401920       // syn [256][512]         (block-private)
#define OFF_MEM   532992       // mem [256][512]         (block-private)
#define OFF_SPPO  664064       // interleaved (spk,post): [256][1024]  (sc1)
#define OFF_TRA   926208       // trA [256][784]         (sc1)
#define OFF_TRB   1126912      // trB [256][784]         (sc1)
#define OFF_WIN   1327616      // int win[256]           (block-private)
#define OFF_ANY   1327872      // u32 anyspk[2][256]     (sc1, ping-pong)
#define OFF_BARF  1328384      // u32 barf[256]: all-to-all barrier flags
#define WS_FLOATS 1332224

// ---- agent-coherent (sc1) access helpers ----
__device__ __forceinline__ float ld_coh(const float* p) {
  return __hip_atomic_load(p, __ATOMIC_RELAXED, __HIP_MEMORY_SCOPE_AGENT);
}
__device__ __forceinline__ float2 ld_coh2(const float* p) {
  union { unsigned long long u; float2 f; } c;
  c.u = __hip_atomic_load((const unsigned long long*)p, __ATOMIC_RELAXED,
                          __HIP_MEMORY_SCOPE_AGENT);
  return c.f;
}
__device__ __forceinline__ void st_coh(float* p, float v) {
  __hip_atomic_store(p, v, __ATOMIC_RELAXED, __HIP_MEMORY_SCOPE_AGENT);
}
__device__ __forceinline__ void st_coh2(float* p, float2 v) {
  union { unsigned long long u; float2 f; } c; c.f = v;
  __hip_atomic_store((unsigned long long*)p, c.u, __ATOMIC_RELAXED,
                     __HIP_MEMORY_SCOPE_AGENT);
}
__device__ __forceinline__ void st_cohu(unsigned* p, unsigned v) {
  __hip_atomic_store(p, v, __ATOMIC_RELAXED, __HIP_MEMORY_SCOPE_AGENT);
}
__device__ __forceinline__ unsigned long long ld_cohu64(const unsigned long long* p) {
  return __hip_atomic_load(p, __ATOMIC_RELAXED, __HIP_MEMORY_SCOPE_AGENT);
}

__device__ __forceinline__ void gl_lds16(const float* g, float* l) {       // cached
  __builtin_amdgcn_global_load_lds(
      (const __attribute__((address_space(1))) void*)g,
      (__attribute__((address_space(3))) void*)l, 16, 0, 0);
}
__device__ __forceinline__ void gl_lds16c(const float* g, float* l) {      // sc1
  __builtin_amdgcn_global_load_lds(
      (const __attribute__((address_space(1))) void*)g,
      (__attribute__((address_space(3))) void*)l, 16, 0, 0x10);
}

// All-to-all flag barrier, k = 1-based ordinal.
__device__ __forceinline__ void gbar(unsigned* barf, unsigned k, int blk) {
  __syncthreads();
  if (threadIdx.x == 0)
    st_cohu(barf + blk, k);
  if (threadIdx.x < 64) {
    const unsigned long long* p =
        (const unsigned long long*)barf + (threadIdx.x << 1);
    for (;;) {
      unsigned long long a = ld_cohu64(p);
      unsigned long long bq = ld_cohu64(p + 1);
      unsigned m0 = (unsigned)a, m1 = (unsigned)(a >> 32);
      unsigned m2 = (unsigned)bq, m3 = (unsigned)(bq >> 32);
      unsigned mn = m0 < m1 ? m0 : m1;
      unsigned mo = m2 < m3 ? m2 : m3;
      mn = mn < mo ? mn : mo;
      if (__all(mn >= k)) break;
      __builtin_amdgcn_s_sleep(1);
    }
  }
  __syncthreads();
}

__global__ void __launch_bounds__(NTHR, 2) snn_kernel(
    const float* __restrict__ img,   // [200][256][784]
    const float* __restrict__ Win,   // [400][784]
    float* __restrict__ out,         // mem_rec | spk_rec | W_final
    float* ws)
{
  float* Wt    = ws + OFF_WT;
  float* syn   = ws + OFF_SYN;
  float* mem   = ws + OFF_MEM;
  float* sppo  = ws + OFF_SPPO;
  float* trA   = ws + OFF_TRA;
  float* trB   = ws + OFF_TRB;
  int*   win   = (int*)(ws + OFF_WIN);
  unsigned* anyspk = (unsigned*)(ws + OFF_ANY);
  unsigned* barf   = (unsigned*)(ws + OFF_BARF);

  float* mem_rec = out;
  float* spk_rec = out + (size_t)T_STEPS * BATCH * NOUT;
  float* Wout    = out + (size_t)2 * T_STEPS * BATCH * NOUT;

  const int tid = threadIdx.x;
  const int blk = blockIdx.x;
  unsigned bt = 0;                    // barrier ordinal

  __shared__ float stg_tr[16384];     // tr  [256][64]  (persistent per step)
  __shared__ float stg_im[16384];     // img [256][64]  (persistent per step)
  __shared__ float stg_sp[3][2048];   // sppo chunk 3-deep pipeline [32][64]
  __shared__ float s_trrow[INQ];      // block-own pre-trace row
  __shared__ int s_list[832];
  __shared__ int s_cnt, s_any;
  __shared__ int s_red[8];

  // phase-2 tile geometry (also used for prefetch); 8 waves
  const int p2w = tid >> 6, p2l = tid & 63;
  const int bi = blk / 13, bn = blk % 13;
  const int ib0 = bi * 64, nb0 = bn * 32;
  int icol = ib0 + (p2l & 15) * 4;
  if (icol > INQ - 4) icol = INQ - 4;           // clamp (garbage, unused)
  const int scol = 2 * nb0 + (p2l & 15) * 4;

  // ---- init: Wt[i][n] = Win[n][i], written coherently ----
  for (int e = blk * NTHR + tid; e < NOUT * INQ; e += GRID * NTHR) {
    int n = e / INQ, i = e % INQ;
    st_coh(Wt + (size_t)i * NP + n, Win[e]);
  }
  for (int i = tid; i < INQ; i += NTHR) s_trrow[i] = 0.0f;
  // prefetch step-0 tr (zeros) + img into persistent LDS (8 passes x 32 rows)
  if (blk < 169) {
    #pragma unroll
    for (int q = 0; q < 8; ++q) {
      int br = q * 32 + p2w * 4 + (p2l >> 4);
      gl_lds16c(trA + (size_t)br * INQ + icol, &stg_tr[(q * 32 + p2w * 4) * 64]);
      gl_lds16 (img + (size_t)br * INQ + icol, &stg_im[(q * 32 + p2w * 4) * 64]);
    }
  }
  ++bt; gbar(barf, bt, blk);

  for (int t = 0; t < T_STEPS; ++t) {
    float* trN = (t & 1) ? trA : trB;   // pre_traces[t+1] global dst

    // ================= phase 1: block b = batch row =================
    {
      const int b = blk;
      const float* imrow = img + ((size_t)t * BATCH + b) * INQ;
      float* trNrow = trN + (size_t)b * INQ;
      if (tid >= 64) {
        // waves 1-7: trace recurrence from block-own LDS row
        for (int i = tid - 64; i < INQ; i += NTHR - 64) {
          float trv = fmaf(0.9f, s_trrow[i], imrow[i]);
          s_trrow[i] = trv;
          st_coh(trNrow + i, trv);
        }
      } else {
        // wave 0: any-spike gather (overlaps compaction), then ordered
        // active-index compaction, padded to multiple of 64
        unsigned long long ax = 0ull, ay = 0ull;
        if (t > 0) {
          const unsigned long long* ap =
              (const unsigned long long*)(anyspk + ((t - 1) & 1) * 256) +
              (tid << 1);
          ax = ld_cohu64(ap);
          ay = ld_cohu64(ap + 1);
        }
        int base = 0;
        for (int c = 0; c < INQ; c += 64) {
          int i = c + tid;
          bool act = (i < INQ) && (imrow[i] != 0.0f);
          unsigned long long m = __ballot(act);
          if (act) s_list[base + (int)__popcll(m & ((1ull << tid) - 1ull))] = i;
          base += (int)__popcll(m);
        }
        int anyv = __any((ax | ay) != 0ull);
        if (tid == 0) {
          int cr = (base + 63) & ~63;
          for (int j = base; j < cr; ++j) s_list[j] = 784;  // zero pad row
          s_cnt = cr;
          s_any = anyv;
        }
      }
      __syncthreads();
      const int cnt = s_cnt;            // multiple of 64
      const int anyPrev = (t > 0) ? s_any : 0;
      const int wPrev = win[b];
      int localmin = 0x7fffffff;

      if (tid < NOUT) {
        const int n0 = tid;             // one neuron per thread
        const size_t sidx = (size_t)b * NP + n0;
        float* sprow = sppo + (size_t)b * 2 * NP + 2 * n0;
        float2 sp2 = ld_coh2(sprow);    // (spk, post)
        float sv = syn[sidx];
        if (anyPrev && n0 != wPrev) sv -= 0.1f;
        float c0 = 0.f;
        for (int j = 0; j < cnt; j += 64) {  // 64 coherent loads in flight
          float wv[64];
          #pragma unroll
          for (int u = 0; u < 64; ++u)
            wv[u] = ld_coh(Wt + (size_t)s_list[j + u] * NP + n0);
          #pragma unroll
          for (int u = 0; u < 64; ++u) c0 += wv[u];
        }
        float mv = mem[sidx];
        float syn0 = fmaf(0.9f, sv, c0);
        float r0 = (mv > 1.0f) ? 1.0f : 0.0f;
        float m0 = fmaf(0.8f, mv, syn0) - r0;
        float s0 = (m0 > 1.0f) ? 1.0f : 0.0f;
        syn[sidx] = syn0;
        mem[sidx] = m0;
        float p0 = fmaf(0.9f, sp2.y, s0);
        st_coh2(sprow, make_float2(s0, p0));
        const size_t ridx = (size_t)t * BATCH * NOUT + (size_t)b * NOUT + n0;
        mem_rec[ridx] = m0;
        spk_rec[ridx] = s0;
        if (s0 != 0.f) localmin = n0;
      }
      // ballot winner reduction
      unsigned long long mm = __ballot(localmin != 0x7fffffff);
      int wmin = 0x7fffffff;
      if (mm) {
        int src = __ffsll(mm) - 1;
        wmin = __shfl(localmin, src);
      }
      if ((tid & 63) == 0) s_red[tid >> 6] = wmin;
      __syncthreads();
      if (tid == 0) {
        int w4 = min(min(min(s_red[0], s_red[1]), min(s_red[2], s_red[3])),
                     min(min(s_red[4], s_red[5]), min(s_red[6], s_red[7])));
        win[b] = (w4 == 0x7fffffff) ? 0 : w4;
        st_cohu(anyspk + (t & 1) * 256 + blk,
                (w4 != 0x7fffffff) ? 1u : 0u);
      }
    }
    ++bt; gbar(barf, bt, blk);

    // ================= phase 2: STDP weight update =================
    if (blk < 169) {
      const int ib = ib0 + (tid >> 4) * 2;     // 2 i-rows per thread
      const int nb = nb0 + (tid & 15) * 2;     // 2 n-cols per thread
      const bool active = (ib < INQ) && (nb < NOUT);
      const int loff = (tid >> 4) * 2;
      const int soff = (tid & 15) * 4;

      float2 wl0, wl1;
      if (active) {
        wl0 = ld_coh2(Wt + (size_t)(ib + 0) * NP + nb);
        wl1 = ld_coh2(Wt + (size_t)(ib + 1) * NP + nb);
      }

      float a00 = 0, a01 = 0, a10 = 0, a11 = 0;
      float z00 = 0, z01 = 0, z10 = 0, z11 = 0;   // dead (measurement)

      #define SPSTG(c_, buf_) {                                                \
        int br = (c_) * 32 + p2w * 4 + (p2l >> 4);                             \
        gl_lds16c(sppo + (size_t)br * 1024 + scol,                             \
                  &stg_sp[buf_][(p2w * 4) * 64]);                              \
      }

      SPSTG(0, 0); SPSTG(1, 1); SPSTG(2, 2);
      for (int c = 0; c < 8; ++c) {
        if (c == 0)      __builtin_amdgcn_s_waitcnt(0x0F72);  // vmcnt(2)
        else if (c < 7)  __builtin_amdgcn_s_waitcnt(0x0F71);  // vmcnt(1)
        else             __builtin_amdgcn_s_waitcnt(0x0F70);  // vmcnt(0)
        __builtin_amdgcn_sched_barrier(0);
        __builtin_amdgcn_s_barrier();
        if (c >= 1 && c <= 5) SPSTG(c + 2, (c + 2) % 3);
        if (active) {
          const float* Ltr = &stg_tr[c * 2048 + loff];
          const float* Lim = &stg_im[c * 2048 + loff];
          const float* Lsp = &stg_sp[c % 3][soff];
          #pragma unroll 4
          for (int bb = 0; bb < 32; ++bb) {       // b ascending: exact order
            float2 t2 = *(const float2*)(Ltr + bb * 64);
            float2 g2 = *(const float2*)(Lim + bb * 64);
            float4 sp = *(const float4*)(Lsp + bb * 64);
            a00 = fmaf(t2.x, sp.x, fmaf(g2.x, -sp.y, a00));
            a01 = fmaf(t2.x, sp.z, fmaf(g2.x, -sp.w, a01));
            a10 = fmaf(t2.y, sp.x, fmaf(g2.y, -sp.y, a10));
            a11 = fmaf(t2.y, sp.z, fmaf(g2.y, -sp.w, a11));
          }
          // ---- MEASUREMENT: duplicated inner loop, dead accumulators ----
          // Laundered offset defeats CSE of the repeated ds_reads; the
          // keep-alive after the chunk loop defeats DCE (rule #17).
          int off2 = 0;
          asm volatile("" : "+v"(off2));
          #pragma unroll 4
          for (int bb = 0; bb < 32; ++bb) {
            float2 t2 = *(const float2*)(Ltr + off2 + bb * 64);
            float2 g2 = *(const float2*)(Lim + off2 + bb * 64);
            float4 sp = *(const float4*)(Lsp + off2 + bb * 64);
            z00 = fmaf(t2.x, sp.x, fmaf(g2.x, -sp.y, z00));
            z01 = fmaf(t2.x, sp.z, fmaf(g2.x, -sp.w, z01));
            z10 = fmaf(t2.y, sp.x, fmaf(g2.y, -sp.y, z10));
            z11 = fmaf(t2.y, sp.z, fmaf(g2.y, -sp.w, z11));
          }
        }
      }
      #undef SPSTG
      asm volatile("" :: "v"(z00), "v"(z01), "v"(z10), "v"(z11));

      // next-step tr/img prefetch streams in the epilogue + barrier shadow
      if (t + 1 < T_STEPS) {
        const float* imn = img + (size_t)(t + 1) * BATCH * INQ;
        #pragma unroll
        for (int q = 0; q < 8; ++q) {
          int br = q * 32 + p2w * 4 + (p2l >> 4);
          gl_lds16c(trN + (size_t)br * INQ + icol,
                    &stg_tr[(q * 32 + p2w * 4) * 64]);
          gl_lds16 (imn + (size_t)br * INQ + icol,
                    &stg_im[(q * 32 + p2w * 4) * 64]);
        }
      }
      if (active) {
        float2 wv;
        wv = wl0;
        wv.x = fminf(fmaxf(wv.x + 1e-3f * a00, 0.f), 1.f);
        wv.y = fminf(fmaxf(wv.y + 1e-3f * a01, 0.f), 1.f);
        st_coh2(Wt + (size_t)(ib + 0) * NP + nb, wv);
        wv = wl1;
        wv.x = fminf(fmaxf(wv.x + 1e-3f * a10, 0.f), 1.f);
        wv.y = fminf(fmaxf(wv.y + 1e-3f * a11, 0.f), 1.f);
        st_coh2(Wt + (size_t)(ib + 1) * NP + nb, wv);
      }
    }
    ++bt; gbar(barf, bt, blk);
  }

  // ---- final: W_out[n][i] = Wt[i][n] ----
  for (int e = blk * NTHR + tid; e < NOUT * INQ; e += GRID * NTHR) {
    int n = e / INQ, i = e % INQ;
    Wout[e] = ld_coh(Wt + (size_t)i * NP + n);
  }
}

extern "C" void kernel_launch(void* const* d_in, const int* in_sizes, int n_in,
                              void* d_out, int out_size, void* d_ws, size_t ws_size,
                              hipStream_t stream) {
  const float* img = (const float*)d_in[0];
  const float* W   = (const float*)d_in[1];
  float* out = (float*)d_out;
  float* ws  = (float*)d_ws;

  hipMemsetAsync(d_ws, 0, (size_t)WS_FLOATS * sizeof(float), stream);

  void* args[] = { (void*)&img, (void*)&W, (void*)&out, (void*)&ws };
  hipError_t rc = hipLaunchCooperativeKernel((const void*)snn_kernel,
                                             dim3(GRID), dim3(NTHR),
                                             args, 0, stream);
  if (rc != hipSuccess) {
    // Hand-rolled grid barrier; ~162 KB LDS -> 1 block/CU, grid == #CUs:
    // co-residency holds by construction under a plain launch.
    hipLaunchKernelGGL(snn_kernel, dim3(GRID), dim3(NTHR), 0, stream,
                       img, W, out, ws);
  }
}

// Round 13
// 7365.632 us; speedup vs baseline: 1.1561x; 1.1561x over previous
//
#include <hip/hip_runtime.h>

// SNN-MNIST forward + STDP, MI355X persistent cooperative kernel.
// Round 17: phase-2 retile driven by r16's measurement (inner loop ~10 of
// 33 us/step, throughput-bound).
//  (1) compute/stage wave split: waves 0-3 compute 4i x 2n per thread
//      (float4 reads, 16 fmaf/bb; r12's proven shape, bb order identical);
//      waves 4-7 exclusively run the sppo 3-deep pipeline (2 loads/chunk,
//      ledger: entry S0-S2; c<=5 vmcnt(4), c=6 vmcnt(2), c=7 vmcnt(0);
//      SPSTG(c+2) after barrier(c) into buf (c-1)%3). LDS bytes/step
//      4.2 MB -> 3.1 MB + 16-lane sppo broadcast dedup.
//  (2) RACE FIX: s_barrier after the chunk loop, before the tr/img
//      prefetch (r15 could overwrite chunk-7 LDS rows under a slow wave;
//      likely cause of absmax 2.0 -> 4.0).
// Phase 1 byte-identical to r15. Belts: __launch_bounds__(512,2),
// coop rc-check fallback, sched_barrier after raw waitcnts.

#define T_STEPS 200
#define BATCH   256
#define INQ     784
#define NOUT    400
#define NP      512
#define GRID    256
#define NTHR    512

// ws layout (float offsets)
#define OFF_WT    0            // Wt [785][512] (row 784 = zero pad for gather)
#define OFF_SYN   401920       // syn [256][512]         (block-private)
#define OFF_MEM   532992       // mem [256][512]         (block-private)
#define OFF_SPPO  664064       // interleaved (spk,post): [256][1024]  (sc1)
#define OFF_TRA   926208       // trA [256][784]         (sc1)
#define OFF_TRB   1126912      // trB [256][784]         (sc1)
#define OFF_WIN   1327616      // int win[256]           (block-private)
#define OFF_ANY   1327872      // u32 anyspk[2][256]     (sc1, ping-pong)
#define OFF_BARF  1328384      // u32 barf[256]: all-to-all barrier flags
#define WS_FLOATS 1332224

// ---- agent-coherent (sc1) access helpers ----
__device__ __forceinline__ float ld_coh(const float* p) {
  return __hip_atomic_load(p, __ATOMIC_RELAXED, __HIP_MEMORY_SCOPE_AGENT);
}
__device__ __forceinline__ float2 ld_coh2(const float* p) {
  union { unsigned long long u; float2 f; } c;
  c.u = __hip_atomic_load((const unsigned long long*)p, __ATOMIC_RELAXED,
                          __HIP_MEMORY_SCOPE_AGENT);
  return c.f;
}
__device__ __forceinline__ void st_coh(float* p, float v) {
  __hip_atomic_store(p, v, __ATOMIC_RELAXED, __HIP_MEMORY_SCOPE_AGENT);
}
__device__ __forceinline__ void st_coh2(float* p, float2 v) {
  union { unsigned long long u; float2 f; } c; c.f = v;
  __hip_atomic_store((unsigned long long*)p, c.u, __ATOMIC_RELAXED,
                     __HIP_MEMORY_SCOPE_AGENT);
}
__device__ __forceinline__ void st_cohu(unsigned* p, unsigned v) {
  __hip_atomic_store(p, v, __ATOMIC_RELAXED, __HIP_MEMORY_SCOPE_AGENT);
}
__device__ __forceinline__ unsigned long long ld_cohu64(const unsigned long long* p) {
  return __hip_atomic_load(p, __ATOMIC_RELAXED, __HIP_MEMORY_SCOPE_AGENT);
}

__device__ __forceinline__ void gl_lds16(const float* g, float* l) {       // cached
  __builtin_amdgcn_global_load_lds(
      (const __attribute__((address_space(1))) void*)g,
      (__attribute__((address_space(3))) void*)l, 16, 0, 0);
}
__device__ __forceinline__ void gl_lds16c(const float* g, float* l) {      // sc1
  __builtin_amdgcn_global_load_lds(
      (const __attribute__((address_space(1))) void*)g,
      (__attribute__((address_space(3))) void*)l, 16, 0, 0x10);
}

// All-to-all flag barrier, k = 1-based ordinal.
__device__ __forceinline__ void gbar(unsigned* barf, unsigned k, int blk) {
  __syncthreads();
  if (threadIdx.x == 0)
    st_cohu(barf + blk, k);
  if (threadIdx.x < 64) {
    const unsigned long long* p =
        (const unsigned long long*)barf + (threadIdx.x << 1);
    for (;;) {
      unsigned long long a = ld_cohu64(p);
      unsigned long long bq = ld_cohu64(p + 1);
      unsigned m0 = (unsigned)a, m1 = (unsigned)(a >> 32);
      unsigned m2 = (unsigned)bq, m3 = (unsigned)(bq >> 32);
      unsigned mn = m0 < m1 ? m0 : m1;
      unsigned mo = m2 < m3 ? m2 : m3;
      mn = mn < mo ? mn : mo;
      if (__all(mn >= k)) break;
      __builtin_amdgcn_s_sleep(1);
    }
  }
  __syncthreads();
}

__global__ void __launch_bounds__(NTHR, 2) snn_kernel(
    const float* __restrict__ img,   // [200][256][784]
    const float* __restrict__ Win,   // [400][784]
    float* __restrict__ out,         // mem_rec | spk_rec | W_final
    float* ws)
{
  float* Wt    = ws + OFF_WT;
  float* syn   = ws + OFF_SYN;
  float* mem   = ws + OFF_MEM;
  float* sppo  = ws + OFF_SPPO;
  float* trA   = ws + OFF_TRA;
  float* trB   = ws + OFF_TRB;
  int*   win   = (int*)(ws + OFF_WIN);
  unsigned* anyspk = (unsigned*)(ws + OFF_ANY);
  unsigned* barf   = (unsigned*)(ws + OFF_BARF);

  float* mem_rec = out;
  float* spk_rec = out + (size_t)T_STEPS * BATCH * NOUT;
  float* Wout    = out + (size_t)2 * T_STEPS * BATCH * NOUT;

  const int tid = threadIdx.x;
  const int blk = blockIdx.x;
  unsigned bt = 0;                    // barrier ordinal

  __shared__ float stg_tr[16384];     // tr  [256][64]  (persistent per step)
  __shared__ float stg_im[16384];     // img [256][64]  (persistent per step)
  __shared__ float stg_sp[3][2048];   // sppo chunk 3-deep pipeline [32][64]
  __shared__ float s_trrow[INQ];      // block-own pre-trace row
  __shared__ int s_list[832];
  __shared__ int s_cnt, s_any;
  __shared__ int s_red[8];

  // phase-2 geometry; 8 waves: 0-3 compute, 4-7 stage
  const int p2w = tid >> 6, p2l = tid & 63;
  const int bi = blk / 13, bn = blk % 13;
  const int ib0 = bi * 64, nb0 = bn * 32;
  int icol = ib0 + (p2l & 15) * 4;
  if (icol > INQ - 4) icol = INQ - 4;           // clamp (garbage, unused)
  const int scol = 2 * nb0 + (p2l & 15) * 4;

  // compute-thread tile (meaningful for tid < 256)
  const int ci  = tid & 255;
  const int cib = ib0 + (ci >> 4) * 4;     // 4 i-rows
  const int cnb = nb0 + (ci & 15) * 2;     // 2 n-cols
  const int loff = (ci >> 4) * 4;
  const int soff = (ci & 15) * 4;

  // ---- init: Wt[i][n] = Win[n][i], written coherently ----
  for (int e = blk * NTHR + tid; e < NOUT * INQ; e += GRID * NTHR) {
    int n = e / INQ, i = e % INQ;
    st_coh(Wt + (size_t)i * NP + n, Win[e]);
  }
  for (int i = tid; i < INQ; i += NTHR) s_trrow[i] = 0.0f;
  // prefetch step-0 tr (zeros) + img into persistent LDS (8 passes x 32 rows)
  if (blk < 169) {
    #pragma unroll
    for (int q = 0; q < 8; ++q) {
      int br = q * 32 + p2w * 4 + (p2l >> 4);
      gl_lds16c(trA + (size_t)br * INQ + icol, &stg_tr[(q * 32 + p2w * 4) * 64]);
      gl_lds16 (img + (size_t)br * INQ + icol, &stg_im[(q * 32 + p2w * 4) * 64]);
    }
  }
  ++bt; gbar(barf, bt, blk);

  for (int t = 0; t < T_STEPS; ++t) {
    float* trN = (t & 1) ? trA : trB;   // pre_traces[t+1] global dst

    // ================= phase 1: block b = batch row =================
    {
      const int b = blk;
      const float* imrow = img + ((size_t)t * BATCH + b) * INQ;
      float* trNrow = trN + (size_t)b * INQ;
      if (tid >= 64) {
        // waves 1-7: trace recurrence from block-own LDS row
        for (int i = tid - 64; i < INQ; i += NTHR - 64) {
          float trv = fmaf(0.9f, s_trrow[i], imrow[i]);
          s_trrow[i] = trv;
          st_coh(trNrow + i, trv);
        }
      } else {
        // wave 0: any-spike gather (overlaps compaction), then ordered
        // active-index compaction, padded to multiple of 64
        unsigned long long ax = 0ull, ay = 0ull;
        if (t > 0) {
          const unsigned long long* ap =
              (const unsigned long long*)(anyspk + ((t - 1) & 1) * 256) +
              (tid << 1);
          ax = ld_cohu64(ap);
          ay = ld_cohu64(ap + 1);
        }
        int base = 0;
        for (int c = 0; c < INQ; c += 64) {
          int i = c + tid;
          bool act = (i < INQ) && (imrow[i] != 0.0f);
          unsigned long long m = __ballot(act);
          if (act) s_list[base + (int)__popcll(m & ((1ull << tid) - 1ull))] = i;
          base += (int)__popcll(m);
        }
        int anyv = __any((ax | ay) != 0ull);
        if (tid == 0) {
          int cr = (base + 63) & ~63;
          for (int j = base; j < cr; ++j) s_list[j] = 784;  // zero pad row
          s_cnt = cr;
          s_any = anyv;
        }
      }
      __syncthreads();
      const int cnt = s_cnt;            // multiple of 64
      const int anyPrev = (t > 0) ? s_any : 0;
      const int wPrev = win[b];
      int localmin = 0x7fffffff;

      if (tid < NOUT) {
        const int n0 = tid;             // one neuron per thread
        const size_t sidx = (size_t)b * NP + n0;
        float* sprow = sppo + (size_t)b * 2 * NP + 2 * n0;
        float2 sp2 = ld_coh2(sprow);    // (spk, post)
        float sv = syn[sidx];
        if (anyPrev && n0 != wPrev) sv -= 0.1f;
        float c0 = 0.f;
        for (int j = 0; j < cnt; j += 64) {  // 64 coherent loads in flight
          float wv[64];
          #pragma unroll
          for (int u = 0; u < 64; ++u)
            wv[u] = ld_coh(Wt + (size_t)s_list[j + u] * NP + n0);
          #pragma unroll
          for (int u = 0; u < 64; ++u) c0 += wv[u];
        }
        float mv = mem[sidx];
        float syn0 = fmaf(0.9f, sv, c0);
        float r0 = (mv > 1.0f) ? 1.0f : 0.0f;
        float m0 = fmaf(0.8f, mv, syn0) - r0;
        float s0 = (m0 > 1.0f) ? 1.0f : 0.0f;
        syn[sidx] = syn0;
        mem[sidx] = m0;
        float p0 = fmaf(0.9f, sp2.y, s0);
        st_coh2(sprow, make_float2(s0, p0));
        const size_t ridx = (size_t)t * BATCH * NOUT + (size_t)b * NOUT + n0;
        mem_rec[ridx] = m0;
        spk_rec[ridx] = s0;
        if (s0 != 0.f) localmin = n0;
      }
      // ballot winner reduction
      unsigned long long mm = __ballot(localmin != 0x7fffffff);
      int wmin = 0x7fffffff;
      if (mm) {
        int src = __ffsll(mm) - 1;
        wmin = __shfl(localmin, src);
      }
      if ((tid & 63) == 0) s_red[tid >> 6] = wmin;
      __syncthreads();
      if (tid == 0) {
        int w4 = min(min(min(s_red[0], s_red[1]), min(s_red[2], s_red[3])),
                     min(min(s_red[4], s_red[5]), min(s_red[6], s_red[7])));
        win[b] = (w4 == 0x7fffffff) ? 0 : w4;
        st_cohu(anyspk + (t & 1) * 256 + blk,
                (w4 != 0x7fffffff) ? 1u : 0u);
      }
    }
    ++bt; gbar(barf, bt, blk);

    // ================= phase 2: STDP weight update =================
    // Waves 0-3 compute (4i x 2n/thread, float4 reads); waves 4-7 run the
    // sppo pipeline exclusively. Single barrier per chunk + trailing
    // barrier before prefetch (race fix).
    if (blk < 169) {
      const bool active = (tid < 256) && (cib < INQ) && (cnb < NOUT);

      float2 wl0, wl1, wl2, wl3;
      if (active) {
        wl0 = ld_coh2(Wt + (size_t)(cib + 0) * NP + cnb);
        wl1 = ld_coh2(Wt + (size_t)(cib + 1) * NP + cnb);
        wl2 = ld_coh2(Wt + (size_t)(cib + 2) * NP + cnb);
        wl3 = ld_coh2(Wt + (size_t)(cib + 3) * NP + cnb);
      }

      float a00=0,a01=0,a10=0,a11=0,a20=0,a21=0,a30=0,a31=0;

      #define SPSTG(c_, buf_) {                                                \
        if (p2w >= 4) {                                                        \
          int sw = p2w - 4;                                                    \
          for (int q = 0; q < 2; ++q) {                                        \
            int br = (c_) * 32 + q * 16 + sw * 4 + (p2l >> 4);                 \
            gl_lds16c(sppo + (size_t)br * 1024 + scol,                         \
                      &stg_sp[buf_][(q * 16 + sw * 4) * 64]);                  \
          }                                                                    \
        }                                                                      \
      }

      SPSTG(0, 0); SPSTG(1, 1); SPSTG(2, 2);
      for (int c = 0; c < 8; ++c) {
        if (p2w >= 4) {                 // stage waves drain their own queue
          if (c <= 5)      __builtin_amdgcn_s_waitcnt(0x0F74);  // vmcnt(4)
          else if (c == 6) __builtin_amdgcn_s_waitcnt(0x0F72);  // vmcnt(2)
          else             __builtin_amdgcn_s_waitcnt(0x0F70);  // vmcnt(0)
        }
        __builtin_amdgcn_sched_barrier(0);
        __builtin_amdgcn_s_barrier();
        if (c >= 1 && c <= 5) SPSTG(c + 2, (c + 2) % 3);
        if (active) {
          const float* Ltr = &stg_tr[c * 2048 + loff];
          const float* Lim = &stg_im[c * 2048 + loff];
          const float* Lsp = &stg_sp[c % 3][soff];
          #pragma unroll 4
          for (int bb = 0; bb < 32; ++bb) {       // b ascending: exact order
            float4 t4 = *(const float4*)(Ltr + bb * 64);
            float4 g4 = *(const float4*)(Lim + bb * 64);
            float4 sp = *(const float4*)(Lsp + bb * 64);
            a00 = fmaf(t4.x, sp.x, fmaf(g4.x, -sp.y, a00));
            a01 = fmaf(t4.x, sp.z, fmaf(g4.x, -sp.w, a01));
            a10 = fmaf(t4.y, sp.x, fmaf(g4.y, -sp.y, a10));
            a11 = fmaf(t4.y, sp.z, fmaf(g4.y, -sp.w, a11));
            a20 = fmaf(t4.z, sp.x, fmaf(g4.z, -sp.y, a20));
            a21 = fmaf(t4.z, sp.z, fmaf(g4.z, -sp.w, a21));
            a30 = fmaf(t4.w, sp.x, fmaf(g4.w, -sp.y, a30));
            a31 = fmaf(t4.w, sp.z, fmaf(g4.w, -sp.w, a31));
          }
        }
      }
      #undef SPSTG

      // RACE FIX: all waves finish chunk-7 LDS reads before prefetch
      // overwrites stg_tr/stg_im.
      __builtin_amdgcn_s_barrier();

      // next-step tr/img prefetch streams in the epilogue + barrier shadow
      if (t + 1 < T_STEPS) {
        const float* imn = img + (size_t)(t + 1) * BATCH * INQ;
        #pragma unroll
        for (int q = 0; q < 8; ++q) {
          int br = q * 32 + p2w * 4 + (p2l >> 4);
          gl_lds16c(trN + (size_t)br * INQ + icol,
                    &stg_tr[(q * 32 + p2w * 4) * 64]);
          gl_lds16 (imn + (size_t)br * INQ + icol,
                    &stg_im[(q * 32 + p2w * 4) * 64]);
        }
      }
      if (active) {
        float accs[4][2] = {{a00,a01},{a10,a11},{a20,a21},{a30,a31}};
        float2 wls[4] = {wl0, wl1, wl2, wl3};
        #pragma unroll
        for (int k = 0; k < 4; ++k) {
          float2 wv = wls[k];
          wv.x = fminf(fmaxf(wv.x + 1e-3f * accs[k][0], 0.f), 1.f);
          wv.y = fminf(fmaxf(wv.y + 1e-3f * accs[k][1], 0.f), 1.f);
          st_coh2(Wt + (size_t)(cib + k) * NP + cnb, wv);
        }
      }
    }
    ++bt; gbar(barf, bt, blk);
  }

  // ---- final: W_out[n][i] = Wt[i][n] ----
  for (int e = blk * NTHR + tid; e < NOUT * INQ; e += GRID * NTHR) {
    int n = e / INQ, i = e % INQ;
    Wout[e] = ld_coh(Wt + (size_t)i * NP + n);
  }
}

extern "C" void kernel_launch(void* const* d_in, const int* in_sizes, int n_in,
                              void* d_out, int out_size, void* d_ws, size_t ws_size,
                              hipStream_t stream) {
  const float* img = (const float*)d_in[0];
  const float* W   = (const float*)d_in[1];
  float* out = (float*)d_out;
  float* ws  = (float*)d_ws;

  hipMemsetAsync(d_ws, 0, (size_t)WS_FLOATS * sizeof(float), stream);

  void* args[] = { (void*)&img, (void*)&W, (void*)&out, (void*)&ws };
  hipError_t rc = hipLaunchCooperativeKernel((const void*)snn_kernel,
                                             dim3(GRID), dim3(NTHR),
                                             args, 0, stream);
  if (rc != hipSuccess) {
    // Hand-rolled grid barrier; ~162 KB LDS -> 1 block/CU, grid == #CUs:
    // co-residency holds by construction under a plain launch.
    hipLaunchKernelGGL(snn_kernel, dim3(GRID), dim3(NTHR), 0, stream,
                       img, W, out, ws);
  }
}

// Round 14
// 6404.755 us; speedup vs baseline: 1.3296x; 1.1500x over previous
//
#include <hip/hip_runtime.h>

// SNN-MNIST forward + STDP, MI355X persistent cooperative kernel.
// Round 18: r15 base (best, 6680 us; r17's wave-split REGRESSED -> all 8
// waves compute again) + three deltas:
//  (1) RACE FIX kept from r17: s_barrier after the chunk loop before the
//      prefetch overwrites stg (r15's absmax 4.0 -> 2.0).
//  (2) MERGED tr|img layout: global trm[b][2i]={tr_(t+1), img_(t+1)} written
//      by phase 1 (img of the NEXT step read from the static input), staged
//      into one stg_ti[256][128] LDS buffer. Phase-2 inner reads become
//      2 x ds_read_b128 per bb (was b64+b64+b128): -33% LDS issue slots.
//      Single tr buffer (trA/trB dropped): nothing reads trC globally;
//      epilogue prefetch drains before the end-of-step gbar, other blocks
//      write only after it.
//  (3) step-0 prefetch moved AFTER the init gbar (merged img written in
//      init); in-order vmcnt retirement keeps the phase-2 ledger intact.
// Per-output arithmetic order identical to r15. Ledger unchanged:
// c=0 vmcnt(2) [wl0,wl1,S0]; c=1..6 vmcnt(1); c=7 vmcnt(0);
// SPSTG(c+2) after barrier(c) into buf (c-1)%3.

#define T_STEPS 200
#define BATCH   256
#define INQ     784
#define NOUT    400
#define NP      512
#define GRID    256
#define NTHR    512

// ws layout (float offsets)
#define OFF_WT    0            // Wt [785][512] (row 784 = zero pad for gather)
#define OFF_SYN   401920       // syn [256][512]         (block-private)
#define OFF_MEM   532992       // mem [256][512]         (block-private)
#define OFF_SPPO  664064       // interleaved (spk,post): [256][1024]  (sc1)
#define OFF_TRM   926208       // merged (tr,img): [256][1568]        (sc1)
#define OFF_WIN   1327616      // int win[256]           (block-private)
#define OFF_ANY   1327872      // u32 anyspk[2][256]     (sc1, ping-pong)
#define OFF_BARF  1328384      // u32 barf[256]: all-to-all barrier flags
#define WS_FLOATS 1332224

// ---- agent-coherent (sc1) access helpers ----
__device__ __forceinline__ float ld_coh(const float* p) {
  return __hip_atomic_load(p, __ATOMIC_RELAXED, __HIP_MEMORY_SCOPE_AGENT);
}
__device__ __forceinline__ float2 ld_coh2(const float* p) {
  union { unsigned long long u; float2 f; } c;
  c.u = __hip_atomic_load((const unsigned long long*)p, __ATOMIC_RELAXED,
                          __HIP_MEMORY_SCOPE_AGENT);
  return c.f;
}
__device__ __forceinline__ void st_coh(float* p, float v) {
  __hip_atomic_store(p, v, __ATOMIC_RELAXED, __HIP_MEMORY_SCOPE_AGENT);
}
__device__ __forceinline__ void st_coh2(float* p, float2 v) {
  union { unsigned long long u; float2 f; } c; c.f = v;
  __hip_atomic_store((unsigned long long*)p, c.u, __ATOMIC_RELAXED,
                     __HIP_MEMORY_SCOPE_AGENT);
}
__device__ __forceinline__ void st_cohu(unsigned* p, unsigned v) {
  __hip_atomic_store(p, v, __ATOMIC_RELAXED, __HIP_MEMORY_SCOPE_AGENT);
}
__device__ __forceinline__ unsigned long long ld_cohu64(const unsigned long long* p) {
  return __hip_atomic_load(p, __ATOMIC_RELAXED, __HIP_MEMORY_SCOPE_AGENT);
}

__device__ __forceinline__ void gl_lds16c(const float* g, float* l) {      // sc1
  __builtin_amdgcn_global_load_lds(
      (const __attribute__((address_space(1))) void*)g,
      (__attribute__((address_space(3))) void*)l, 16, 0, 0x10);
}

// All-to-all flag barrier, k = 1-based ordinal.
__device__ __forceinline__ void gbar(unsigned* barf, unsigned k, int blk) {
  __syncthreads();
  if (threadIdx.x == 0)
    st_cohu(barf + blk, k);
  if (threadIdx.x < 64) {
    const unsigned long long* p =
        (const unsigned long long*)barf + (threadIdx.x << 1);
    for (;;) {
      unsigned long long a = ld_cohu64(p);
      unsigned long long bq = ld_cohu64(p + 1);
      unsigned m0 = (unsigned)a, m1 = (unsigned)(a >> 32);
      unsigned m2 = (unsigned)bq, m3 = (unsigned)(bq >> 32);
      unsigned mn = m0 < m1 ? m0 : m1;
      unsigned mo = m2 < m3 ? m2 : m3;
      mn = mn < mo ? mn : mo;
      if (__all(mn >= k)) break;
      __builtin_amdgcn_s_sleep(1);
    }
  }
  __syncthreads();
}

__global__ void __launch_bounds__(NTHR, 2) snn_kernel(
    const float* __restrict__ img,   // [200][256][784]
    const float* __restrict__ Win,   // [400][784]
    float* __restrict__ out,         // mem_rec | spk_rec | W_final
    float* ws)
{
  float* Wt    = ws + OFF_WT;
  float* syn   = ws + OFF_SYN;
  float* mem   = ws + OFF_MEM;
  float* sppo  = ws + OFF_SPPO;
  float* trm   = ws + OFF_TRM;
  int*   win   = (int*)(ws + OFF_WIN);
  unsigned* anyspk = (unsigned*)(ws + OFF_ANY);
  unsigned* barf   = (unsigned*)(ws + OFF_BARF);

  float* mem_rec = out;
  float* spk_rec = out + (size_t)T_STEPS * BATCH * NOUT;
  float* Wout    = out + (size_t)2 * T_STEPS * BATCH * NOUT;

  const int tid = threadIdx.x;
  const int blk = blockIdx.x;
  unsigned bt = 0;                    // barrier ordinal

  __shared__ float stg_ti[32768];     // merged (tr,img) [256][128], persistent
  __shared__ float stg_sp[3][2048];   // sppo chunk 3-deep pipeline [32][64]
  __shared__ float s_trrow[INQ];      // block-own pre-trace row
  __shared__ int s_list[832];
  __shared__ int s_cnt, s_any;
  __shared__ int s_red[8];

  // phase-2 geometry; 8 waves, all compute + all stage
  const int p2w = tid >> 6, p2l = tid & 63;
  const int bi = blk / 13, bn = blk % 13;
  const int ib0 = bi * 64, nb0 = bn * 32;
  const int scol = 2 * nb0 + (p2l & 15) * 4;
  // merged-column float offset for prefetch (clamped; garbage cols unused)
  int colf = 2 * ib0 + (tid & 31) * 4;
  if (colf > 2 * INQ - 4) colf = 2 * INQ - 4;

  // ---- init: Wt[i][n] = Win[n][i]; merged row {tr=0, img_0} ----
  for (int e = blk * NTHR + tid; e < NOUT * INQ; e += GRID * NTHR) {
    int n = e / INQ, i = e % INQ;
    st_coh(Wt + (size_t)i * NP + n, Win[e]);
  }
  for (int i = tid; i < INQ; i += NTHR)
    st_coh2(trm + (size_t)blk * (2 * INQ) + 2 * i,
            make_float2(0.0f, img[(size_t)blk * INQ + i]));
  for (int i = tid; i < INQ; i += NTHR) s_trrow[i] = 0.0f;
  ++bt; gbar(barf, bt, blk);

  // step-0 prefetch: merged tile into persistent LDS (16 passes x 16 rows)
  if (blk < 169) {
    #pragma unroll
    for (int q = 0; q < 16; ++q) {
      int br = q * 16 + (tid >> 5);
      gl_lds16c(trm + (size_t)br * (2 * INQ) + colf,
                &stg_ti[br * 128 + (tid & 31) * 4]);
    }
  }

  for (int t = 0; t < T_STEPS; ++t) {
    // ================= phase 1: block b = batch row =================
    {
      const int b = blk;
      const float* imrow = img + ((size_t)t * BATCH + b) * INQ;
      const float* imnext =
          img + ((size_t)((t + 1 < T_STEPS) ? t + 1 : t) * BATCH + b) * INQ;
      float* trmrow = trm + (size_t)b * (2 * INQ);
      if (tid >= 64) {
        // waves 1-7: trace recurrence from block-own LDS row; write merged
        // {tr_{t+1}, img_{t+1}} pair for next step's phase 2
        for (int i = tid - 64; i < INQ; i += NTHR - 64) {
          float trv = fmaf(0.9f, s_trrow[i], imrow[i]);
          s_trrow[i] = trv;
          st_coh2(trmrow + 2 * i, make_float2(trv, imnext[i]));
        }
      } else {
        // wave 0: any-spike gather (overlaps compaction), then ordered
        // active-index compaction, padded to multiple of 64
        unsigned long long ax = 0ull, ay = 0ull;
        if (t > 0) {
          const unsigned long long* ap =
              (const unsigned long long*)(anyspk + ((t - 1) & 1) * 256) +
              (tid << 1);
          ax = ld_cohu64(ap);
          ay = ld_cohu64(ap + 1);
        }
        int base = 0;
        for (int c = 0; c < INQ; c += 64) {
          int i = c + tid;
          bool act = (i < INQ) && (imrow[i] != 0.0f);
          unsigned long long m = __ballot(act);
          if (act) s_list[base + (int)__popcll(m & ((1ull << tid) - 1ull))] = i;
          base += (int)__popcll(m);
        }
        int anyv = __any((ax | ay) != 0ull);
        if (tid == 0) {
          int cr = (base + 63) & ~63;
          for (int j = base; j < cr; ++j) s_list[j] = 784;  // zero pad row
          s_cnt = cr;
          s_any = anyv;
        }
      }
      __syncthreads();
      const int cnt = s_cnt;            // multiple of 64
      const int anyPrev = (t > 0) ? s_any : 0;
      const int wPrev = win[b];
      int localmin = 0x7fffffff;

      if (tid < NOUT) {
        const int n0 = tid;             // one neuron per thread
        const size_t sidx = (size_t)b * NP + n0;
        float* sprow = sppo + (size_t)b * 2 * NP + 2 * n0;
        float2 sp2 = ld_coh2(sprow);    // (spk, post)
        float sv = syn[sidx];
        if (anyPrev && n0 != wPrev) sv -= 0.1f;
        float c0 = 0.f;
        for (int j = 0; j < cnt; j += 64) {  // 64 coherent loads in flight
          float wv[64];
          #pragma unroll
          for (int u = 0; u < 64; ++u)
            wv[u] = ld_coh(Wt + (size_t)s_list[j + u] * NP + n0);
          #pragma unroll
          for (int u = 0; u < 64; ++u) c0 += wv[u];
        }
        float mv = mem[sidx];
        float syn0 = fmaf(0.9f, sv, c0);
        float r0 = (mv > 1.0f) ? 1.0f : 0.0f;
        float m0 = fmaf(0.8f, mv, syn0) - r0;
        float s0 = (m0 > 1.0f) ? 1.0f : 0.0f;
        syn[sidx] = syn0;
        mem[sidx] = m0;
        float p0 = fmaf(0.9f, sp2.y, s0);
        st_coh2(sprow, make_float2(s0, p0));
        const size_t ridx = (size_t)t * BATCH * NOUT + (size_t)b * NOUT + n0;
        mem_rec[ridx] = m0;
        spk_rec[ridx] = s0;
        if (s0 != 0.f) localmin = n0;
      }
      // ballot winner reduction
      unsigned long long mm = __ballot(localmin != 0x7fffffff);
      int wmin = 0x7fffffff;
      if (mm) {
        int src = __ffsll(mm) - 1;
        wmin = __shfl(localmin, src);
      }
      if ((tid & 63) == 0) s_red[tid >> 6] = wmin;
      __syncthreads();
      if (tid == 0) {
        int w4 = min(min(min(s_red[0], s_red[1]), min(s_red[2], s_red[3])),
                     min(min(s_red[4], s_red[5]), min(s_red[6], s_red[7])));
        win[b] = (w4 == 0x7fffffff) ? 0 : w4;
        st_cohu(anyspk + (t & 1) * 256 + blk,
                (w4 != 0x7fffffff) ? 1u : 0u);
      }
    }
    ++bt; gbar(barf, bt, blk);

    // ================= phase 2: STDP weight update =================
    // Merged stg_ti resident. Wt RMW loads FIRST (oldest in queue); sppo
    // single-barrier 3-deep pipeline; every wave stages 1 load/chunk.
    if (blk < 169) {
      const int ib = ib0 + (tid >> 4) * 2;     // 2 i-rows per thread
      const int nb = nb0 + (tid & 15) * 2;     // 2 n-cols per thread
      const bool active = (ib < INQ) && (nb < NOUT);
      const int tioff = (tid >> 4) * 4;        // merged float offset (16B)
      const int soff = (tid & 15) * 4;

      float2 wl0, wl1;
      if (active) {
        wl0 = ld_coh2(Wt + (size_t)(ib + 0) * NP + nb);
        wl1 = ld_coh2(Wt + (size_t)(ib + 1) * NP + nb);
      }

      float a00 = 0, a01 = 0, a10 = 0, a11 = 0;

      #define SPSTG(c_, buf_) {                                                \
        int br = (c_) * 32 + p2w * 4 + (p2l >> 4);                             \
        gl_lds16c(sppo + (size_t)br * 1024 + scol,                             \
                  &stg_sp[buf_][(p2w * 4) * 64]);                              \
      }

      SPSTG(0, 0); SPSTG(1, 1); SPSTG(2, 2);
      for (int c = 0; c < 8; ++c) {
        if (c == 0)      __builtin_amdgcn_s_waitcnt(0x0F72);  // vmcnt(2)
        else if (c < 7)  __builtin_amdgcn_s_waitcnt(0x0F71);  // vmcnt(1)
        else             __builtin_amdgcn_s_waitcnt(0x0F70);  // vmcnt(0)
        __builtin_amdgcn_sched_barrier(0);
        __builtin_amdgcn_s_barrier();
        if (c >= 1 && c <= 5) SPSTG(c + 2, (c + 2) % 3);
        if (active) {
          const float* Lti = &stg_ti[(c * 32) * 128 + tioff];
          const float* Lsp = &stg_sp[c % 3][soff];
          #pragma unroll 8
          for (int bb = 0; bb < 32; ++bb) {       // b ascending: exact order
            float4 q4 = *(const float4*)(Lti + bb * 128);  // tr0,im0,tr1,im1
            float4 sp = *(const float4*)(Lsp + bb * 64);   // s0,p0,s1,p1
            a00 = fmaf(q4.x, sp.x, fmaf(q4.y, -sp.y, a00));
            a01 = fmaf(q4.x, sp.z, fmaf(q4.y, -sp.w, a01));
            a10 = fmaf(q4.z, sp.x, fmaf(q4.w, -sp.y, a10));
            a11 = fmaf(q4.z, sp.z, fmaf(q4.w, -sp.w, a11));
          }
        }
      }
      #undef SPSTG

      // RACE FIX: all waves finish chunk-7 LDS reads before the prefetch
      // overwrites stg_ti.
      __builtin_amdgcn_s_barrier();

      // next-step merged prefetch streams in the epilogue + barrier shadow
      if (t + 1 < T_STEPS) {
        #pragma unroll
        for (int q = 0; q < 16; ++q) {
          int br = q * 16 + (tid >> 5);
          gl_lds16c(trm + (size_t)br * (2 * INQ) + colf,
                    &stg_ti[br * 128 + (tid & 31) * 4]);
        }
      }
      if (active) {
        float2 wv;
        wv = wl0;
        wv.x = fminf(fmaxf(wv.x + 1e-3f * a00, 0.f), 1.f);
        wv.y = fminf(fmaxf(wv.y + 1e-3f * a01, 0.f), 1.f);
        st_coh2(Wt + (size_t)(ib + 0) * NP + nb, wv);
        wv = wl1;
        wv.x = fminf(fmaxf(wv.x + 1e-3f * a10, 0.f), 1.f);
        wv.y = fminf(fmaxf(wv.y + 1e-3f * a11, 0.f), 1.f);
        st_coh2(Wt + (size_t)(ib + 1) * NP + nb, wv);
      }
    }
    ++bt; gbar(barf, bt, blk);
  }

  // ---- final: W_out[n][i] = Wt[i][n] ----
  for (int e = blk * NTHR + tid; e < NOUT * INQ; e += GRID * NTHR) {
    int n = e / INQ, i = e % INQ;
    Wout[e] = ld_coh(Wt + (size_t)i * NP + n);
  }
}

extern "C" void kernel_launch(void* const* d_in, const int* in_sizes, int n_in,
                              void* d_out, int out_size, void* d_ws, size_t ws_size,
                              hipStream_t stream) {
  const float* img = (const float*)d_in[0];
  const float* W   = (const float*)d_in[1];
  float* out = (float*)d_out;
  float* ws  = (float*)d_ws;

  hipMemsetAsync(d_ws, 0, (size_t)WS_FLOATS * sizeof(float), stream);

  void* args[] = { (void*)&img, (void*)&W, (void*)&out, (void*)&ws };
  hipError_t rc = hipLaunchCooperativeKernel((const void*)snn_kernel,
                                             dim3(GRID), dim3(NTHR),
                                             args, 0, stream);
  if (rc != hipSuccess) {
    // Hand-rolled grid barrier; ~159 KB LDS -> 1 block/CU, grid == #CUs:
    // co-residency holds by construction under a plain launch.
    hipLaunchKernelGGL(snn_kernel, dim3(GRID), dim3(NTHR), 0, stream,
                       img, W, out, ws);
  }
}